// Round 1
// 467.696 us; speedup vs baseline: 1.0531x; 1.0531x over previous
//
#include <hip/hip_runtime.h>

// Per-joint 3D Euclidean distance, mean over B*21 joints.
// B = 1048576, NUM_JOINTS = 21 -> 66,060,288 fp32 per input (252 MiB each).
// Streaming-read reduction; floor ~= 528 MB / 6.8 TB/s ~= 78 us.
//
// R4: fully-coalesced nt loads + in-register ds_bpermute redistribution.
// Prior rounds: R1 (48B-stride direct) == R2 (coalesced+LDS+barriers) == R3
// (48B-stride + nt) == ~492-500 us total. Remaining theory: with a 48B lane
// stride each 64B line is touched by TWO load instructions, so (a) every
// dwordx4 is a 48-line partial-line gather and (b) the nt evict-first hint
// can drop a line between its two touches -> re-fetch. Here each 64B line is
// covered by exactly ONE lane of ONE instruction, exactly once -> nt is
// line-exact: stream past L2/L3 without evicting dirty poison lines and
// without re-touch.
//
// Joint layout fixup done in-register: compute s=(p-t)^2 componentwise
// (perfectly aligned, no cross-lane), THEN redistribute only s via
// ds_bpermute (36/iter; ~12% LDS-pipe, ~5% VALU at HBM pace -> still
// memory-bound). No LDS arrays, no __syncthreads in the main loop.
//
// Wave chunk = 192 f32x4 = 768 floats = 256 joints; lane owns joints
// [4*lane, 4*lane+4) = s-vectors u = 3*lane+j, j=0..2, pulled from
// phase-reg u>>6 at source lane u&63.

#define TPB 256
#define BLOCKS 2048  // 8 blocks/CU, 32 waves/CU

typedef float f32x4 __attribute__((ext_vector_type(4)));

__global__ __launch_bounds__(TPB) void joint_dist_kernel(
    const float* __restrict__ pred,
    const float* __restrict__ target,
    float* __restrict__ out,
    int nchunks,        // number of 768-float chunks (exactly divisible)
    float inv_count)
{
    const f32x4* __restrict__ p4 = (const f32x4*)pred;
    const f32x4* __restrict__ t4 = (const f32x4*)target;

    const int lane   = threadIdx.x & 63;
    const int wave   = (blockIdx.x * TPB + threadIdx.x) >> 6;
    const int nwaves = (gridDim.x * TPB) >> 6;

    // Per-lane-constant redistribution pattern (hoisted out of the loop):
    // lane needs s-vectors u = 3*lane + j of its wave's 192-vector chunk.
    int addr0, addr1, addr2;   // ds_bpermute byte addr = (u & 63) * 4
    int r0, r1, r2;            // which phase register holds u: u >> 6
    {
        int u0 = 3 * lane + 0, u1 = 3 * lane + 1, u2 = 3 * lane + 2;
        addr0 = (u0 & 63) << 2; r0 = u0 >> 6;
        addr1 = (u1 & 63) << 2; r1 = u1 >> 6;
        addr2 = (u2 & 63) << 2; r2 = u2 >> 6;
    }

    float acc = 0.0f;
    for (int c = wave; c < nchunks; c += nwaves) {
        const int base = c * 192 + lane;
        // Coalesced: lane stride 16 B, each 64 B line read once by one instr.
        f32x4 pa0 = __builtin_nontemporal_load(&p4[base]);
        f32x4 pa1 = __builtin_nontemporal_load(&p4[base + 64]);
        f32x4 pa2 = __builtin_nontemporal_load(&p4[base + 128]);
        f32x4 tb0 = __builtin_nontemporal_load(&t4[base]);
        f32x4 tb1 = __builtin_nontemporal_load(&t4[base + 64]);
        f32x4 tb2 = __builtin_nontemporal_load(&t4[base + 128]);

        // Componentwise: indices of p and t align, no cross-lane needed yet.
        f32x4 d0 = pa0 - tb0, d1 = pa1 - tb1, d2 = pa2 - tb2;
        f32x4 s0 = d0 * d0,   s1 = d1 * d1,   s2 = d2 * d2;

        // Redistribute ONLY the squares: lane pulls s-vectors 3l, 3l+1, 3l+2.
        float o[12];
        #pragma unroll
        for (int k = 0; k < 4; ++k) {
            {
                int x0 = __builtin_amdgcn_ds_bpermute(addr0, __float_as_int(s0[k]));
                int x1 = __builtin_amdgcn_ds_bpermute(addr0, __float_as_int(s1[k]));
                int x2 = __builtin_amdgcn_ds_bpermute(addr0, __float_as_int(s2[k]));
                o[0 * 4 + k] = __int_as_float(r0 == 0 ? x0 : (r0 == 1 ? x1 : x2));
            }
            {
                int x0 = __builtin_amdgcn_ds_bpermute(addr1, __float_as_int(s0[k]));
                int x1 = __builtin_amdgcn_ds_bpermute(addr1, __float_as_int(s1[k]));
                int x2 = __builtin_amdgcn_ds_bpermute(addr1, __float_as_int(s2[k]));
                o[1 * 4 + k] = __int_as_float(r1 == 0 ? x0 : (r1 == 1 ? x1 : x2));
            }
            {
                int x0 = __builtin_amdgcn_ds_bpermute(addr2, __float_as_int(s0[k]));
                int x1 = __builtin_amdgcn_ds_bpermute(addr2, __float_as_int(s1[k]));
                int x2 = __builtin_amdgcn_ds_bpermute(addr2, __float_as_int(s2[k]));
                o[2 * 4 + k] = __int_as_float(r2 == 0 ? x0 : (r2 == 1 ? x1 : x2));
            }
        }

        // Lane-local floats [12l, 12l+12) = joints 4l..4l+3.
        acc += sqrtf(o[0] + o[1]  + o[2]);
        acc += sqrtf(o[3] + o[4]  + o[5]);
        acc += sqrtf(o[6] + o[7]  + o[8]);
        acc += sqrtf(o[9] + o[10] + o[11]);
    }

    // 64-lane wave reduction
    #pragma unroll
    for (int off = 32; off > 0; off >>= 1)
        acc += __shfl_down(acc, off, 64);

    __shared__ float wsum[TPB / 64];
    int wid = threadIdx.x >> 6;
    if (lane == 0) wsum[wid] = acc;
    __syncthreads();

    if (threadIdx.x == 0) {
        // One device-scope atomic per block; pre-scaled so out == mean.
        // d_out poison 0xAAAAAAAA == -3.03e-13f: absorbed, << threshold.
        float bsum = wsum[0] + wsum[1] + wsum[2] + wsum[3];
        atomicAdd(out, bsum * inv_count);
    }
}

extern "C" void kernel_launch(void* const* d_in, const int* in_sizes, int n_in,
                              void* d_out, int out_size, void* d_ws, size_t ws_size,
                              hipStream_t stream) {
    const float* pred   = (const float*)d_in[0];
    const float* target = (const float*)d_in[1];
    float* out = (float*)d_out;

    int total_floats = in_sizes[0];         // 66,060,288
    int nchunks      = total_floats / 768;  // 86,016 (exact)
    int njoints      = total_floats / 3;    // 22,020,096

    joint_dist_kernel<<<BLOCKS, TPB, 0, stream>>>(pred, target, out, nchunks,
                                                  1.0f / (float)njoints);
}

// Round 4
// 465.109 us; speedup vs baseline: 1.0590x; 1.0056x over previous
//
#include <hip/hip_runtime.h>

// Per-joint 3D Euclidean distance, mean over B*21 joints.
// B = 1048576, NUM_JOINTS = 21 -> 66,060,288 fp32 per input (252 MiB each).
// Streaming-read reduction; floor ~= 528 MB / 6.8 TB/s ~= 78 us.
//
// R7 == R6 == R5. R5/R6 never executed: broker "container failed twice"
// with NO timing block -> failure at container acquire, before our source
// was compiled. Infra flake, not kernel defect. Third attempt.
// History: R1 (strided) == R2 (LDS) == R3 (strided+nt) ~= 492-500;
// R4 (coalesced nt + ds_bpermute redistribution) = 467.7 (-25).
// Theory: the variant-invariant residue (~50-70 us over floor) is the 2048
// atomicAdds to ONE global address at kernel end: device-scope RMWs from 8
// non-coherent XCDs serialize at a single coherence point, and balanced
// blocks finish in a burst -> pure tail latency ~25-35 ns/op.
// Fix: per-block partials in d_ws (plain stores, zero atomics) + tiny
// graph-captured reduce kernel (~3 us).
// Also: BLOCKS 2048 -> 1792 (7/CU, 224/XCD). nwaves = 7168 and
// 86016 chunks / 7168 = 12.0 exactly -> no half-wave tail iteration
// (was 10.5 -> ~5% imbalance).
// Robustness: if ws_size < BLOCKS*4 (unexpected), fall back to the proven
// R4 single-kernel atomic path instead of dereferencing d_ws.

#define TPB 256
#define BLOCKS 1792  // 7 blocks/CU; 86016 wave-chunks / 7168 waves = 12 exact

typedef float f32x4 __attribute__((ext_vector_type(4)));

// USE_WS=1: write per-block partial to partials[blockIdx.x] (no atomics).
// USE_WS=0: atomicAdd(out, bsum * inv_count)  (R4 behavior).
template <int USE_WS>
__global__ __launch_bounds__(TPB) void joint_dist_kernel(
    const float* __restrict__ pred,
    const float* __restrict__ target,
    float* __restrict__ sink,   // partials (USE_WS) or out (atomic path)
    int nchunks,                // number of 768-float chunks (exactly divisible)
    float inv_count)
{
    const f32x4* __restrict__ p4 = (const f32x4*)pred;
    const f32x4* __restrict__ t4 = (const f32x4*)target;

    const int lane   = threadIdx.x & 63;
    const int wave   = (blockIdx.x * TPB + threadIdx.x) >> 6;
    const int nwaves = (gridDim.x * TPB) >> 6;

    // Per-lane-constant redistribution pattern (hoisted out of the loop):
    // lane needs s-vectors u = 3*lane + j of its wave's 192-vector chunk.
    int addr0, addr1, addr2;   // ds_bpermute byte addr = (u & 63) * 4
    int r0, r1, r2;            // which phase register holds u: u >> 6
    {
        int u0 = 3 * lane + 0, u1 = 3 * lane + 1, u2 = 3 * lane + 2;
        addr0 = (u0 & 63) << 2; r0 = u0 >> 6;
        addr1 = (u1 & 63) << 2; r1 = u1 >> 6;
        addr2 = (u2 & 63) << 2; r2 = u2 >> 6;
    }

    float acc = 0.0f;
    for (int c = wave; c < nchunks; c += nwaves) {
        const int base = c * 192 + lane;
        // Coalesced: lane stride 16 B, each 64 B line read once by one instr.
        // nt: line-exact streaming, no L2/L3 allocation or victim evictions.
        f32x4 pa0 = __builtin_nontemporal_load(&p4[base]);
        f32x4 pa1 = __builtin_nontemporal_load(&p4[base + 64]);
        f32x4 pa2 = __builtin_nontemporal_load(&p4[base + 128]);
        f32x4 tb0 = __builtin_nontemporal_load(&t4[base]);
        f32x4 tb1 = __builtin_nontemporal_load(&t4[base + 64]);
        f32x4 tb2 = __builtin_nontemporal_load(&t4[base + 128]);

        // Componentwise: indices of p and t align, no cross-lane needed yet.
        f32x4 d0 = pa0 - tb0, d1 = pa1 - tb1, d2 = pa2 - tb2;
        f32x4 s0 = d0 * d0,   s1 = d1 * d1,   s2 = d2 * d2;

        // Redistribute ONLY the squares: lane pulls s-vectors 3l, 3l+1, 3l+2.
        float o[12];
        #pragma unroll
        for (int k = 0; k < 4; ++k) {
            {
                int x0 = __builtin_amdgcn_ds_bpermute(addr0, __float_as_int(s0[k]));
                int x1 = __builtin_amdgcn_ds_bpermute(addr0, __float_as_int(s1[k]));
                int x2 = __builtin_amdgcn_ds_bpermute(addr0, __float_as_int(s2[k]));
                o[0 * 4 + k] = __int_as_float(r0 == 0 ? x0 : (r0 == 1 ? x1 : x2));
            }
            {
                int x0 = __builtin_amdgcn_ds_bpermute(addr1, __float_as_int(s0[k]));
                int x1 = __builtin_amdgcn_ds_bpermute(addr1, __float_as_int(s1[k]));
                int x2 = __builtin_amdgcn_ds_bpermute(addr1, __float_as_int(s2[k]));
                o[1 * 4 + k] = __int_as_float(r1 == 0 ? x0 : (r1 == 1 ? x1 : x2));
            }
            {
                int x0 = __builtin_amdgcn_ds_bpermute(addr2, __float_as_int(s0[k]));
                int x1 = __builtin_amdgcn_ds_bpermute(addr2, __float_as_int(s1[k]));
                int x2 = __builtin_amdgcn_ds_bpermute(addr2, __float_as_int(s2[k]));
                o[2 * 4 + k] = __int_as_float(r2 == 0 ? x0 : (r2 == 1 ? x1 : x2));
            }
        }

        // Lane-local floats [12l, 12l+12) = joints 4l..4l+3.
        acc += sqrtf(o[0] + o[1]  + o[2]);
        acc += sqrtf(o[3] + o[4]  + o[5]);
        acc += sqrtf(o[6] + o[7]  + o[8]);
        acc += sqrtf(o[9] + o[10] + o[11]);
    }

    // 64-lane wave reduction
    #pragma unroll
    for (int off = 32; off > 0; off >>= 1)
        acc += __shfl_down(acc, off, 64);

    __shared__ float wsum[TPB / 64];
    int wid = threadIdx.x >> 6;
    if (lane == 0) wsum[wid] = acc;
    __syncthreads();

    if (threadIdx.x == 0) {
        float bsum = wsum[0] + wsum[1] + wsum[2] + wsum[3];
        if (USE_WS) {
            // Plain store to a private slot: ZERO atomics, no cross-XCD
            // same-address serialization.
            sink[blockIdx.x] = bsum;
        } else {
            // Fallback (R4): d_out poison 0xAAAAAAAA == -3.03e-13f absorbed.
            atomicAdd(sink, bsum * inv_count);
        }
    }
}

__global__ __launch_bounds__(TPB) void reduce_kernel(
    const float* __restrict__ partials,
    float* __restrict__ out,
    float inv_count)
{
    float acc = 0.0f;
    for (int i = threadIdx.x; i < BLOCKS; i += TPB)
        acc += partials[i];

    #pragma unroll
    for (int off = 32; off > 0; off >>= 1)
        acc += __shfl_down(acc, off, 64);

    __shared__ float wsum[TPB / 64];
    int lane = threadIdx.x & 63;
    int wid  = threadIdx.x >> 6;
    if (lane == 0) wsum[wid] = acc;
    __syncthreads();

    if (threadIdx.x == 0) {
        // Plain store (overwrites d_out poison exactly).
        out[0] = (wsum[0] + wsum[1] + wsum[2] + wsum[3]) * inv_count;
    }
}

extern "C" void kernel_launch(void* const* d_in, const int* in_sizes, int n_in,
                              void* d_out, int out_size, void* d_ws, size_t ws_size,
                              hipStream_t stream) {
    const float* pred   = (const float*)d_in[0];
    const float* target = (const float*)d_in[1];
    float* out      = (float*)d_out;
    float* partials = (float*)d_ws;   // BLOCKS * 4 B = 7 KiB

    int total_floats = in_sizes[0];         // 66,060,288
    int nchunks      = total_floats / 768;  // 86,016 (exact)
    int njoints      = total_floats / 3;    // 22,020,096
    float inv_count  = 1.0f / (float)njoints;

    if (d_ws != nullptr && ws_size >= BLOCKS * sizeof(float)) {
        joint_dist_kernel<1><<<BLOCKS, TPB, 0, stream>>>(pred, target, partials,
                                                         nchunks, inv_count);
        reduce_kernel<<<1, TPB, 0, stream>>>(partials, out, inv_count);
    } else {
        // Fallback: proven R4 single-kernel atomic path (no workspace use).
        joint_dist_kernel<0><<<BLOCKS, TPB, 0, stream>>>(pred, target, out,
                                                         nchunks, inv_count);
    }
}

// Round 5
// 461.384 us; speedup vs baseline: 1.0675x; 1.0081x over previous
//
#include <hip/hip_runtime.h>

// Per-joint 3D Euclidean distance, mean over B*21 joints.
// B = 1048576, NUM_JOINTS = 21 -> 66,060,288 fp32 per input (252 MiB each).
// Streaming-read reduction; floor ~= 528 MB / 6.8 TB/s ~= 78 us.
//
// R8: DIAGNOSTIC ROUND (deliberate, bounded regression).
// History: R1 (strided) == R2 (LDS) == R3 (strided+nt) ~= 492-500;
// R4 (coalesced nt + ds_bpermute) = 467.7; R5/R7 (no atomics, exact
// balance) = 465.1 -> atomic-tail theory dead (delta -2.6 us < noise).
// Problem: the kernel has NEVER been directly observed — top-5 is always
// ~160 us harness fills, and the kernel (<159 us) hides below them. The
// total-only inference can't distinguish "kernel ~140 us (3.8 TB/s, 60 us
// headroom)" from "kernel ~90 us (at floor, rest is hidden harness ops)".
// Fix: BLOCKS 1792 -> 512 (2/CU; 86016/2048 waves = 42.0 exact, balance
// preserved). Kernel slows to ~170-300 us -> enters top-5 WITH its own
// counter row: direct FETCH_SIZE (over-fetch?), direct hbm_gbps, and
// kernel_old = kernel_new - (total_new - total_old).
// Body is byte-identical to R7. Single variable: grid size.

#define TPB 256
#define BLOCKS 512   // DIAGNOSTIC: 2 blocks/CU; 86016/2048 waves = 42 exact

typedef float f32x4 __attribute__((ext_vector_type(4)));

// USE_WS=1: write per-block partial to partials[blockIdx.x] (no atomics).
// USE_WS=0: atomicAdd(out, bsum * inv_count)  (R4 behavior).
template <int USE_WS>
__global__ __launch_bounds__(TPB) void joint_dist_kernel(
    const float* __restrict__ pred,
    const float* __restrict__ target,
    float* __restrict__ sink,   // partials (USE_WS) or out (atomic path)
    int nchunks,                // number of 768-float chunks (exactly divisible)
    float inv_count)
{
    const f32x4* __restrict__ p4 = (const f32x4*)pred;
    const f32x4* __restrict__ t4 = (const f32x4*)target;

    const int lane   = threadIdx.x & 63;
    const int wave   = (blockIdx.x * TPB + threadIdx.x) >> 6;
    const int nwaves = (gridDim.x * TPB) >> 6;

    // Per-lane-constant redistribution pattern (hoisted out of the loop):
    // lane needs s-vectors u = 3*lane + j of its wave's 192-vector chunk.
    int addr0, addr1, addr2;   // ds_bpermute byte addr = (u & 63) * 4
    int r0, r1, r2;            // which phase register holds u: u >> 6
    {
        int u0 = 3 * lane + 0, u1 = 3 * lane + 1, u2 = 3 * lane + 2;
        addr0 = (u0 & 63) << 2; r0 = u0 >> 6;
        addr1 = (u1 & 63) << 2; r1 = u1 >> 6;
        addr2 = (u2 & 63) << 2; r2 = u2 >> 6;
    }

    float acc = 0.0f;
    for (int c = wave; c < nchunks; c += nwaves) {
        const int base = c * 192 + lane;
        // Coalesced: lane stride 16 B, each 64 B line read once by one instr.
        // nt: line-exact streaming, no L2/L3 allocation or victim evictions.
        f32x4 pa0 = __builtin_nontemporal_load(&p4[base]);
        f32x4 pa1 = __builtin_nontemporal_load(&p4[base + 64]);
        f32x4 pa2 = __builtin_nontemporal_load(&p4[base + 128]);
        f32x4 tb0 = __builtin_nontemporal_load(&t4[base]);
        f32x4 tb1 = __builtin_nontemporal_load(&t4[base + 64]);
        f32x4 tb2 = __builtin_nontemporal_load(&t4[base + 128]);

        // Componentwise: indices of p and t align, no cross-lane needed yet.
        f32x4 d0 = pa0 - tb0, d1 = pa1 - tb1, d2 = pa2 - tb2;
        f32x4 s0 = d0 * d0,   s1 = d1 * d1,   s2 = d2 * d2;

        // Redistribute ONLY the squares: lane pulls s-vectors 3l, 3l+1, 3l+2.
        float o[12];
        #pragma unroll
        for (int k = 0; k < 4; ++k) {
            {
                int x0 = __builtin_amdgcn_ds_bpermute(addr0, __float_as_int(s0[k]));
                int x1 = __builtin_amdgcn_ds_bpermute(addr0, __float_as_int(s1[k]));
                int x2 = __builtin_amdgcn_ds_bpermute(addr0, __float_as_int(s2[k]));
                o[0 * 4 + k] = __int_as_float(r0 == 0 ? x0 : (r0 == 1 ? x1 : x2));
            }
            {
                int x0 = __builtin_amdgcn_ds_bpermute(addr1, __float_as_int(s0[k]));
                int x1 = __builtin_amdgcn_ds_bpermute(addr1, __float_as_int(s1[k]));
                int x2 = __builtin_amdgcn_ds_bpermute(addr1, __float_as_int(s2[k]));
                o[1 * 4 + k] = __int_as_float(r1 == 0 ? x0 : (r1 == 1 ? x1 : x2));
            }
            {
                int x0 = __builtin_amdgcn_ds_bpermute(addr2, __float_as_int(s0[k]));
                int x1 = __builtin_amdgcn_ds_bpermute(addr2, __float_as_int(s1[k]));
                int x2 = __builtin_amdgcn_ds_bpermute(addr2, __float_as_int(s2[k]));
                o[2 * 4 + k] = __int_as_float(r2 == 0 ? x0 : (r2 == 1 ? x1 : x2));
            }
        }

        // Lane-local floats [12l, 12l+12) = joints 4l..4l+3.
        acc += sqrtf(o[0] + o[1]  + o[2]);
        acc += sqrtf(o[3] + o[4]  + o[5]);
        acc += sqrtf(o[6] + o[7]  + o[8]);
        acc += sqrtf(o[9] + o[10] + o[11]);
    }

    // 64-lane wave reduction
    #pragma unroll
    for (int off = 32; off > 0; off >>= 1)
        acc += __shfl_down(acc, off, 64);

    __shared__ float wsum[TPB / 64];
    int wid = threadIdx.x >> 6;
    if (lane == 0) wsum[wid] = acc;
    __syncthreads();

    if (threadIdx.x == 0) {
        float bsum = wsum[0] + wsum[1] + wsum[2] + wsum[3];
        if (USE_WS) {
            // Plain store to a private slot: ZERO atomics, no cross-XCD
            // same-address serialization.
            sink[blockIdx.x] = bsum;
        } else {
            // Fallback (R4): d_out poison 0xAAAAAAAA == -3.03e-13f absorbed.
            atomicAdd(sink, bsum * inv_count);
        }
    }
}

__global__ __launch_bounds__(TPB) void reduce_kernel(
    const float* __restrict__ partials,
    float* __restrict__ out,
    float inv_count)
{
    float acc = 0.0f;
    for (int i = threadIdx.x; i < BLOCKS; i += TPB)
        acc += partials[i];

    #pragma unroll
    for (int off = 32; off > 0; off >>= 1)
        acc += __shfl_down(acc, off, 64);

    __shared__ float wsum[TPB / 64];
    int lane = threadIdx.x & 63;
    int wid  = threadIdx.x >> 6;
    if (lane == 0) wsum[wid] = acc;
    __syncthreads();

    if (threadIdx.x == 0) {
        // Plain store (overwrites d_out poison exactly).
        out[0] = (wsum[0] + wsum[1] + wsum[2] + wsum[3]) * inv_count;
    }
}

extern "C" void kernel_launch(void* const* d_in, const int* in_sizes, int n_in,
                              void* d_out, int out_size, void* d_ws, size_t ws_size,
                              hipStream_t stream) {
    const float* pred   = (const float*)d_in[0];
    const float* target = (const float*)d_in[1];
    float* out      = (float*)d_out;
    float* partials = (float*)d_ws;   // BLOCKS * 4 B

    int total_floats = in_sizes[0];         // 66,060,288
    int nchunks      = total_floats / 768;  // 86,016 (exact)
    int njoints      = total_floats / 3;    // 22,020,096
    float inv_count  = 1.0f / (float)njoints;

    if (d_ws != nullptr && ws_size >= BLOCKS * sizeof(float)) {
        joint_dist_kernel<1><<<BLOCKS, TPB, 0, stream>>>(pred, target, partials,
                                                         nchunks, inv_count);
        reduce_kernel<<<1, TPB, 0, stream>>>(partials, out, inv_count);
    } else {
        // Fallback: proven R4 single-kernel atomic path (no workspace use).
        joint_dist_kernel<0><<<BLOCKS, TPB, 0, stream>>>(pred, target, out,
                                                         nchunks, inv_count);
    }
}